// Round 12
// baseline (138.025 us; speedup 1.0000x reference)
//
#include <hip/hip_runtime.h>

// Problem constants: B=2, T=2048, C=1024, H=16, S=64
#define BB 2
#define TT 2048
#define CC 1024
#define HH 16
#define SS 64
#define MM (BB * TT)   // 4096

typedef unsigned short u16;
typedef __bf16 bf16x8 __attribute__((ext_vector_type(8)));
typedef float f32x4 __attribute__((ext_vector_type(4)));
typedef float f32x16 __attribute__((ext_vector_type(16)));

#define MFMA16(a, b, c) __builtin_amdgcn_mfma_f32_16x16x32_bf16((a), (b), (c), 0, 0, 0)
#define MFMA32(a, b, c) __builtin_amdgcn_mfma_f32_32x32x16_bf16((a), (b), (c), 0, 0, 0)
// v_cvt_pk_bf16_f32: D[15:0]=bf16(S0), D[31:16]=bf16(S1)
#define CVTPK(d, a, b) asm("v_cvt_pk_bf16_f32 %0, %1, %2" : "=v"(d) : "v"(a), "v"(b))

__device__ inline u16 f2bf(float f) {
    union { float f; unsigned u; } v;
    v.f = f;
    unsigned r = v.u + 0x7FFFu + ((v.u >> 16) & 1u);
    return (u16)(r >> 16);
}

// ---------------------------------------------------------------- fused casts
__global__ __launch_bounds__(256) void cast_all(
    const float4* __restrict__ x,  const float4* __restrict__ wq,
    const float4* __restrict__ wk, const float4* __restrict__ wv,
    const float4* __restrict__ wo,
    ushort4* __restrict__ xo, ushort4* __restrict__ qo,
    ushort4* __restrict__ ko, ushort4* __restrict__ vo,
    ushort4* __restrict__ oo) {
    int bid = blockIdx.x;
    const float4* src; ushort4* dst; int i;
    if (bid < 4096) {
        src = x; dst = xo; i = bid * 256 + threadIdx.x;
    } else {
        int s = (bid - 4096) >> 10;
        int r = (bid - 4096) & 1023;
        src = (s == 0) ? wq : (s == 1) ? wk : (s == 2) ? wv : wo;
        dst = (s == 0) ? qo : (s == 1) ? ko : (s == 2) ? vo : oo;
        i = r * 256 + threadIdx.x;
    }
    float4 v = src[i];
    ushort4 o;
    o.x = f2bf(v.x); o.y = f2bf(v.y); o.z = f2bf(v.z); o.w = f2bf(v.w);
    dst[i] = o;
}

// ---------------------------------------------------------------- 128x128 GEMM core
__device__ __forceinline__ void stage_tile(const u16* __restrict__ g, int row0, int k0,
                                           u16* lds) {
    int t = threadIdx.x;
#pragma unroll
    for (int q = 0; q < 2; ++q) {
        int idx = q * 256 + t;
        int row = idx >> 2;
        int chunk = (idx & 3) ^ (row & 3);
        const u16* src = g + (long)(row0 + row) * CC + k0 + chunk * 8;
        __builtin_amdgcn_global_load_lds(
            (const __attribute__((address_space(1))) void*)src,
            (__attribute__((address_space(3))) void*)(lds + idx * 8), 16, 0, 0);
    }
}

__device__ __forceinline__ void gemm_core(const u16* __restrict__ A,
                                          const u16* __restrict__ Bt,
                                          int blkM, int blkN,
                                          u16* sA0, u16* sB0, u16* sA1, u16* sB1,
                                          f32x4 (&acc)[4][4]) {
    int lane = threadIdx.x & 63;
    int w = threadIdx.x >> 6;
    int wr = w >> 1, wc = w & 1;
    int l15 = lane & 15;
    int hi = lane >> 4;

#pragma unroll
    for (int m = 0; m < 4; ++m)
#pragma unroll
        for (int n = 0; n < 4; ++n) acc[m][n] = (f32x4){0.f, 0.f, 0.f, 0.f};

    stage_tile(A, blkM * 128, 0, sA0);
    stage_tile(Bt, blkN * 128, 0, sB0);

    for (int kt = 0; kt < CC / 32; ++kt) {
        __syncthreads();
        u16* cA = (kt & 1) ? sA1 : sA0;
        u16* cB = (kt & 1) ? sB1 : sB0;
        if (kt + 1 < CC / 32) {
            u16* nA = (kt & 1) ? sA0 : sA1;
            u16* nB = (kt & 1) ? sB0 : sB1;
            stage_tile(A, blkM * 128, (kt + 1) * 32, nA);
            stage_tile(Bt, blkN * 128, (kt + 1) * 32, nB);
        }
        bf16x8 af[4], bfr[4];
#pragma unroll
        for (int m = 0; m < 4; ++m) {
            int row = wr * 64 + m * 16 + l15;
            af[m] = *(const bf16x8*)(cA + row * 32 + ((hi ^ (row & 3)) << 3));
        }
#pragma unroll
        for (int n = 0; n < 4; ++n) {
            int row = wc * 64 + n * 16 + l15;
            bfr[n] = *(const bf16x8*)(cB + row * 32 + ((hi ^ (row & 3)) << 3));
        }
#pragma unroll
        for (int m = 0; m < 4; ++m)
#pragma unroll
            for (int n = 0; n < 4; ++n)
                acc[m][n] = MFMA16(af[m], bfr[n], acc[m][n]);
    }
}

__global__ __launch_bounds__(256) void qkv_gemm(const u16* __restrict__ xb,
                                                const u16* __restrict__ wqb,
                                                const u16* __restrict__ wkb,
                                                const u16* __restrict__ wvb,
                                                u16* __restrict__ qo,
                                                u16* __restrict__ ko,
                                                u16* __restrict__ vt) {
    __shared__ u16 smem[4][128 * 32];
    int seg = blockIdx.x >> 8;
    int bid = blockIdx.x & 255;
    int blkM = bid & 31, blkN = bid >> 5;
    const u16* Bt = (seg == 0) ? wqb : (seg == 1) ? wkb : wvb;
    f32x4 acc[4][4];
    gemm_core(xb, Bt, blkM, blkN, smem[0], smem[1], smem[2], smem[3], acc);

    int lane = threadIdx.x & 63;
    int w = threadIdx.x >> 6, wr = w >> 1, wc = w & 1;
    int l15 = lane & 15, hi = lane >> 4;
    int r0 = blkM * 128 + wr * 64 + hi * 4;
    int c0 = blkN * 128 + wc * 64 + l15;

    if (seg == 2) {
#pragma unroll
        for (int m = 0; m < 4; ++m)
#pragma unroll
            for (int n = 0; n < 4; ++n) {
                ushort4 p;
                p.x = f2bf(acc[m][n][0]); p.y = f2bf(acc[m][n][1]);
                p.z = f2bf(acc[m][n][2]); p.w = f2bf(acc[m][n][3]);
                *(ushort4*)(vt + (long)(c0 + n * 16) * MM + r0 + m * 16) = p;
            }
    } else {
        u16* dst = (seg == 0) ? qo : ko;
        // Q pre-scaled by 1/sqrt(64) * log2(e): exp2-domain softmax
        float sc = (seg == 0) ? 0.18033688011112042f : 1.0f;
#pragma unroll
        for (int m = 0; m < 4; ++m)
#pragma unroll
            for (int n = 0; n < 4; ++n)
#pragma unroll
                for (int i = 0; i < 4; ++i)
                    dst[(long)(r0 + m * 16 + i) * CC + c0 + n * 16] =
                        f2bf(acc[m][n][i] * sc);
    }
}

__global__ __launch_bounds__(256) void out_gemm(const u16* __restrict__ at,
                                                const u16* __restrict__ wob,
                                                const float* __restrict__ bias,
                                                float* __restrict__ out) {
    __shared__ u16 smem[4][128 * 32];
    int bid = blockIdx.x;
    int blkM = bid & 31, blkN = bid >> 5;
    f32x4 acc[4][4];
    gemm_core(at, wob, blkM, blkN, smem[0], smem[1], smem[2], smem[3], acc);

    int lane = threadIdx.x & 63;
    int w = threadIdx.x >> 6, wr = w >> 1, wc = w & 1;
    int l15 = lane & 15, hi = lane >> 4;
    int r0 = blkM * 128 + wr * 64 + hi * 4;
    int c0 = blkN * 128 + wc * 64 + l15;
#pragma unroll
    for (int n = 0; n < 4; ++n) {
        int c = c0 + n * 16;
        float bv = bias[c];
#pragma unroll
        for (int m = 0; m < 4; ++m)
#pragma unroll
            for (int i = 0; i < 4; ++i)
                out[(long)(r0 + m * 16 + i) * CC + c] = acc[m][n][i] + bv;
    }
}

// ---------------------------------------------------------------- flash attention v12
// NO K/V LDS staging, NO per-tile barriers: K and V fragments are per-lane
// contiguous 16B loads straight from global (L2-resident via XCD-local bh).
// Block = 2 waves on the same 32 q-rows; wave w handles 32-kv subtiles
// tt = w, w+2, ... (v8's split). P per-wave LDS roundtrip (lgkm only).
// One barrier pair at the end for the 2-way merge.
#define PSTR2 36   // P row stride (u16): 72B, 8B-aligned

__global__ __launch_bounds__(128, 4) void attn_fwd(const u16* __restrict__ Q,
                                                   const u16* __restrict__ Kb,
                                                   const u16* __restrict__ Vt,
                                                   u16* __restrict__ O) {
    __shared__ u16 sP[2][32 * PSTR2];   // 4.6 KB
    __shared__ float xch[64 * 36];      // 9.2 KB merge scratch
    int lane = threadIdx.x & 63;
    int w = threadIdx.x >> 6;           // 0..1 = kv-parity
    int bh = blockIdx.x & 31;           // same bh -> same XCD (idx&7 = bh&7)
    int qt = 63 - (blockIdx.x >> 5);    // q-tile of 32 rows, heaviest first (LPT)
    int h = bh & 15, b = bh >> 4;
    int l31 = lane & 31, h5 = lane >> 5;

    int qg = qt * 32 + l31;             // this lane's q row
    int nt32 = qt + 1;                  // 32-kv subtiles total
    u16* Pw = sP[w];

    // fragment base pointers (per-lane 16B-contiguous)
    // K: row kv, cols h*64 + m*16 + h5*8
    const u16* kp = Kb + (long)(b * TT + w * 32 + l31) * CC + h * SS + h5 * 8;
    // Vt: row h*64+d, cols b*TT + kv + 16s + 8h5
    const u16* vp0 = Vt + (long)(h * SS + l31) * MM + b * TT + w * 32 + h5 * 8;
    const u16* vp1 = Vt + (long)(h * SS + 32 + l31) * MM + b * TT + w * 32 + h5 * 8;

    // Q fragments (B operand): col=l31 (q), k = m*16 + h5*8 + j
    const u16* qrow = Q + (long)(b * TT + qg) * CC + h * SS + h5 * 8;
    bf16x8 qf[4];
#pragma unroll
    for (int m = 0; m < 4; ++m) qf[m] = *(const bf16x8*)(qrow + m * 16);

    f32x16 oa0 = {0.f}, oa1 = {0.f};    // O^T partial: d 0..31 / 32..63, col=q=l31
    float mr = -1e30f, lr = 0.f;

#pragma unroll 1
    for (int tt = w; tt < nt32; tt += 2) {
        // K fragments: A rows = kv (tt*32 + l31), k-chunks m*16 + h5*8
        bf16x8 kf0 = *(const bf16x8*)(kp);
        bf16x8 kf1 = *(const bf16x8*)(kp + 16);
        bf16x8 kf2 = *(const bf16x8*)(kp + 32);
        bf16x8 kf3 = *(const bf16x8*)(kp + 48);
        // V fragments (hoisted; independent of scores)
        bf16x8 vf00 = *(const bf16x8*)(vp0);        // d=l31,    kv s=0
        bf16x8 vf01 = *(const bf16x8*)(vp0 + 16);   //           kv s=1
        bf16x8 vf10 = *(const bf16x8*)(vp1);        // d=32+l31, kv s=0
        bf16x8 vf11 = *(const bf16x8*)(vp1 + 16);
        kp += 64 * CC;
        vp0 += 64;
        vp1 += 64;

        // QK^T swapped: S^T = mfma(A=K, B=Q)
        f32x16 s0 = {0.f};
        s0 = MFMA32(kf0, qf[0], s0);
        s0 = MFMA32(kf1, qf[1], s0);
        s0 = MFMA32(kf2, qf[2], s0);
        s0 = MFMA32(kf3, qf[3], s0);

        if (tt == qt) {   // diagonal subtile: causal mask (kv > q)
            int kvb = tt * 32 + 4 * h5;
#pragma unroll
            for (int r = 0; r < 16; ++r) {
                int kv = kvb + (r & 3) + 8 * (r >> 2);
                if (kv > qg) s0[r] = -1e30f;
            }
        }

        // subtile max: in-lane tree + one partner exchange
        float t8[8];
#pragma unroll
        for (int r = 0; r < 8; ++r) t8[r] = fmaxf(s0[r], s0[r + 8]);
#pragma unroll
        for (int r = 0; r < 4; ++r) t8[r] = fmaxf(t8[r], t8[r + 4]);
        float tmx = fmaxf(fmaxf(t8[0], t8[1]), fmaxf(t8[2], t8[3]));
        tmx = fmaxf(tmx, __shfl_xor(tmx, 32));

        // defer-max: rescale only when subtile max exceeds running max by > 8
        if (!__all(tmx <= mr + 8.0f)) {
            float mnew = fmaxf(mr, tmx);
            float scl = __builtin_amdgcn_exp2f(mr - mnew);
            lr *= scl;
#pragma unroll
            for (int r = 0; r < 16; ++r) { oa0[r] *= scl; oa1[r] *= scl; }
            mr = mnew;
        }

        // P = exp2(S - mr), bounded by 2^8
        f32x16 p0v;
#pragma unroll
        for (int r = 0; r < 16; ++r) p0v[r] = __builtin_amdgcn_exp2f(s0[r] - mr);
        float sm[8];
#pragma unroll
        for (int r = 0; r < 8; ++r) sm[r] = p0v[r] + p0v[r + 8];
#pragma unroll
        for (int r = 0; r < 4; ++r) sm[r] = sm[r] + sm[r + 4];
        float rs = (sm[0] + sm[1]) + (sm[2] + sm[3]);
        rs += __shfl_xor(rs, 32);
        lr += rs;

        // P -> LDS [q=l31][kv 0..31], packed via cvt_pk (low u16 = src0)
#pragma unroll
        for (int r4 = 0; r4 < 4; ++r4) {
            unsigned a0, a1;
            CVTPK(a0, p0v[r4 * 4 + 0], p0v[r4 * 4 + 1]);
            CVTPK(a1, p0v[r4 * 4 + 2], p0v[r4 * 4 + 3]);
            uint2 ua;
            ua.x = a0; ua.y = a1;
            *(uint2*)(Pw + l31 * PSTR2 + 8 * r4 + 4 * h5) = ua;
        }

        // PV: O^T[d][q] += V[d][kv] * P^T[kv][q]
        bf16x8 pf0 = *(const bf16x8*)(Pw + l31 * PSTR2 + 8 * h5);        // s=0
        bf16x8 pf1 = *(const bf16x8*)(Pw + l31 * PSTR2 + 16 + 8 * h5);   // s=1
        oa0 = MFMA32(vf00, pf0, oa0);
        oa0 = MFMA32(vf01, pf1, oa0);
        oa1 = MFMA32(vf10, pf0, oa1);
        oa1 = MFMA32(vf11, pf1, oa1);
    }

    // ---- merge the two kv-parity partials (per-lane elementwise; same layout) ----
    if (w == 1) {
        float* xl = xch + lane * 36;
#pragma unroll
        for (int r = 0; r < 16; ++r) { xl[r] = oa0[r]; xl[16 + r] = oa1[r]; }
        xl[32] = mr; xl[33] = lr;
    }
    __syncthreads();
    if (w == 0) {
        float* xl = xch + lane * 36;
        float m1 = xl[32], l1 = xl[33];
        float m = fmaxf(mr, m1);
        float e0 = __builtin_amdgcn_exp2f(mr - m);
        float e1 = __builtin_amdgcn_exp2f(m1 - m);
        float inv = 1.0f / (lr * e0 + l1 * e1);
        float f0 = e0 * inv, f1 = e1 * inv;

        u16* ob = O + (long)(b * TT + qg) * CC + h * SS;
#pragma unroll
        for (int rq = 0; rq < 4; ++rq) {
            float v00 = oa0[rq * 4 + 0] * f0 + xl[rq * 4 + 0] * f1;
            float v01 = oa0[rq * 4 + 1] * f0 + xl[rq * 4 + 1] * f1;
            float v02 = oa0[rq * 4 + 2] * f0 + xl[rq * 4 + 2] * f1;
            float v03 = oa0[rq * 4 + 3] * f0 + xl[rq * 4 + 3] * f1;
            float v10 = oa1[rq * 4 + 0] * f0 + xl[16 + rq * 4 + 0] * f1;
            float v11 = oa1[rq * 4 + 1] * f0 + xl[16 + rq * 4 + 1] * f1;
            float v12 = oa1[rq * 4 + 2] * f0 + xl[16 + rq * 4 + 2] * f1;
            float v13 = oa1[rq * 4 + 3] * f0 + xl[16 + rq * 4 + 3] * f1;
            unsigned a0, a1, c0, c1;
            CVTPK(a0, v00, v01);
            CVTPK(a1, v02, v03);
            CVTPK(c0, v10, v11);
            CVTPK(c1, v12, v13);
            uint2 ua, uc;
            ua.x = a0; ua.y = a1; uc.x = c0; uc.y = c1;
            *(uint2*)(ob + rq * 8 + h5 * 4) = ua;
            *(uint2*)(ob + 32 + rq * 8 + h5 * 4) = uc;
        }
    }
}

// ---------------------------------------------------------------- launch
extern "C" void kernel_launch(void* const* d_in, const int* in_sizes, int n_in,
                              void* d_out, int out_size, void* d_ws, size_t ws_size,
                              hipStream_t stream) {
    const float* x  = (const float*)d_in[0];
    const float* Wq = (const float*)d_in[1];
    const float* Wk = (const float*)d_in[2];
    const float* Wv = (const float*)d_in[3];
    const float* Wo = (const float*)d_in[4];
    const float* bo = (const float*)d_in[5];

    char* ws = (char*)d_ws;
    const size_t MB = 1024 * 1024;
    u16* x_bf  = (u16*)(ws);
    u16* wq_bf = (u16*)(ws + 8 * MB);
    u16* wk_bf = (u16*)(ws + 10 * MB);
    u16* wv_bf = (u16*)(ws + 12 * MB);
    u16* wo_bf = (u16*)(ws + 14 * MB);
    u16* q_bf  = (u16*)(ws + 16 * MB);
    u16* k_bf  = (u16*)(ws + 24 * MB);
    u16* vt_bf = (u16*)(ws + 32 * MB);   // [1024][4096] transposed V
    u16* at_bf = (u16*)(ws + 40 * MB);

    cast_all<<<dim3(8192), dim3(256), 0, stream>>>(
        (const float4*)x, (const float4*)Wq, (const float4*)Wk,
        (const float4*)Wv, (const float4*)Wo,
        (ushort4*)x_bf, (ushort4*)wq_bf, (ushort4*)wk_bf,
        (ushort4*)wv_bf, (ushort4*)wo_bf);

    qkv_gemm<<<dim3(768), dim3(256), 0, stream>>>(x_bf, wq_bf, wk_bf, wv_bf,
                                                  q_bf, k_bf, vt_bf);

    attn_fwd<<<dim3(2048), dim3(128), 0, stream>>>(q_bf, k_bf, vt_bf, at_bf);

    out_gemm<<<dim3(256), dim3(256), 0, stream>>>(at_bf, wo_bf, bo, (float*)d_out);
}

// Round 13
// 121.181 us; speedup vs baseline: 1.1390x; 1.1390x over previous
//
#include <hip/hip_runtime.h>

// Problem constants: B=2, T=2048, C=1024, H=16, S=64
#define BB 2
#define TT 2048
#define CC 1024
#define HH 16
#define SS 64
#define MM (BB * TT)   // 4096

typedef unsigned short u16;
typedef __bf16 bf16x8 __attribute__((ext_vector_type(8)));
typedef float f32x4 __attribute__((ext_vector_type(4)));
typedef float f32x16 __attribute__((ext_vector_type(16)));

#define MFMA16(a, b, c) __builtin_amdgcn_mfma_f32_16x16x32_bf16((a), (b), (c), 0, 0, 0)
#define MFMA32(a, b, c) __builtin_amdgcn_mfma_f32_32x32x16_bf16((a), (b), (c), 0, 0, 0)
// v_cvt_pk_bf16_f32: D[15:0]=bf16(S0), D[31:16]=bf16(S1)
#define CVTPK(d, a, b) asm("v_cvt_pk_bf16_f32 %0, %1, %2" : "=v"(d) : "v"(a), "v"(b))

__device__ inline u16 f2bf(float f) {
    union { float f; unsigned u; } v;
    v.f = f;
    unsigned r = v.u + 0x7FFFu + ((v.u >> 16) & 1u);
    return (u16)(r >> 16);
}

// ---------------------------------------------------------------- fused casts
__global__ __launch_bounds__(256) void cast_all(
    const float4* __restrict__ x,  const float4* __restrict__ wq,
    const float4* __restrict__ wk, const float4* __restrict__ wv,
    const float4* __restrict__ wo,
    ushort4* __restrict__ xo, ushort4* __restrict__ qo,
    ushort4* __restrict__ ko, ushort4* __restrict__ vo,
    ushort4* __restrict__ oo) {
    int bid = blockIdx.x;
    const float4* src; ushort4* dst; int i;
    if (bid < 4096) {
        src = x; dst = xo; i = bid * 256 + threadIdx.x;
    } else {
        int s = (bid - 4096) >> 10;
        int r = (bid - 4096) & 1023;
        src = (s == 0) ? wq : (s == 1) ? wk : (s == 2) ? wv : wo;
        dst = (s == 0) ? qo : (s == 1) ? ko : (s == 2) ? vo : oo;
        i = r * 256 + threadIdx.x;
    }
    float4 v = src[i];
    ushort4 o;
    o.x = f2bf(v.x); o.y = f2bf(v.y); o.z = f2bf(v.z); o.w = f2bf(v.w);
    dst[i] = o;
}

// ---------------------------------------------------------------- 128x128 GEMM core
__device__ __forceinline__ void stage_tile(const u16* __restrict__ g, int row0, int k0,
                                           u16* lds) {
    int t = threadIdx.x;
#pragma unroll
    for (int q = 0; q < 2; ++q) {
        int idx = q * 256 + t;
        int row = idx >> 2;
        int chunk = (idx & 3) ^ (row & 3);
        const u16* src = g + (long)(row0 + row) * CC + k0 + chunk * 8;
        __builtin_amdgcn_global_load_lds(
            (const __attribute__((address_space(1))) void*)src,
            (__attribute__((address_space(3))) void*)(lds + idx * 8), 16, 0, 0);
    }
}

__device__ __forceinline__ void gemm_core(const u16* __restrict__ A,
                                          const u16* __restrict__ Bt,
                                          int blkM, int blkN,
                                          u16* sA0, u16* sB0, u16* sA1, u16* sB1,
                                          f32x4 (&acc)[4][4]) {
    int lane = threadIdx.x & 63;
    int w = threadIdx.x >> 6;
    int wr = w >> 1, wc = w & 1;
    int l15 = lane & 15;
    int hi = lane >> 4;

#pragma unroll
    for (int m = 0; m < 4; ++m)
#pragma unroll
        for (int n = 0; n < 4; ++n) acc[m][n] = (f32x4){0.f, 0.f, 0.f, 0.f};

    stage_tile(A, blkM * 128, 0, sA0);
    stage_tile(Bt, blkN * 128, 0, sB0);

    for (int kt = 0; kt < CC / 32; ++kt) {
        __syncthreads();
        u16* cA = (kt & 1) ? sA1 : sA0;
        u16* cB = (kt & 1) ? sB1 : sB0;
        if (kt + 1 < CC / 32) {
            u16* nA = (kt & 1) ? sA0 : sA1;
            u16* nB = (kt & 1) ? sB0 : sB1;
            stage_tile(A, blkM * 128, (kt + 1) * 32, nA);
            stage_tile(Bt, blkN * 128, (kt + 1) * 32, nB);
        }
        bf16x8 af[4], bfr[4];
#pragma unroll
        for (int m = 0; m < 4; ++m) {
            int row = wr * 64 + m * 16 + l15;
            af[m] = *(const bf16x8*)(cA + row * 32 + ((hi ^ (row & 3)) << 3));
        }
#pragma unroll
        for (int n = 0; n < 4; ++n) {
            int row = wc * 64 + n * 16 + l15;
            bfr[n] = *(const bf16x8*)(cB + row * 32 + ((hi ^ (row & 3)) << 3));
        }
#pragma unroll
        for (int m = 0; m < 4; ++m)
#pragma unroll
            for (int n = 0; n < 4; ++n)
                acc[m][n] = MFMA16(af[m], bfr[n], acc[m][n]);
    }
}

__global__ __launch_bounds__(256) void qkv_gemm(const u16* __restrict__ xb,
                                                const u16* __restrict__ wqb,
                                                const u16* __restrict__ wkb,
                                                const u16* __restrict__ wvb,
                                                u16* __restrict__ qo,
                                                u16* __restrict__ ko,
                                                u16* __restrict__ vt) {
    __shared__ u16 smem[4][128 * 32];
    int seg = blockIdx.x >> 8;
    int bid = blockIdx.x & 255;
    int blkM = bid & 31, blkN = bid >> 5;
    const u16* Bt = (seg == 0) ? wqb : (seg == 1) ? wkb : wvb;
    f32x4 acc[4][4];
    gemm_core(xb, Bt, blkM, blkN, smem[0], smem[1], smem[2], smem[3], acc);

    int lane = threadIdx.x & 63;
    int w = threadIdx.x >> 6, wr = w >> 1, wc = w & 1;
    int l15 = lane & 15, hi = lane >> 4;
    int r0 = blkM * 128 + wr * 64 + hi * 4;
    int c0 = blkN * 128 + wc * 64 + l15;

    if (seg == 2) {
#pragma unroll
        for (int m = 0; m < 4; ++m)
#pragma unroll
            for (int n = 0; n < 4; ++n) {
                ushort4 p;
                p.x = f2bf(acc[m][n][0]); p.y = f2bf(acc[m][n][1]);
                p.z = f2bf(acc[m][n][2]); p.w = f2bf(acc[m][n][3]);
                *(ushort4*)(vt + (long)(c0 + n * 16) * MM + r0 + m * 16) = p;
            }
    } else {
        u16* dst = (seg == 0) ? qo : ko;
        // Q pre-scaled by 1/sqrt(64) * log2(e): exp2-domain softmax
        float sc = (seg == 0) ? 0.18033688011112042f : 1.0f;
#pragma unroll
        for (int m = 0; m < 4; ++m)
#pragma unroll
            for (int n = 0; n < 4; ++n)
#pragma unroll
                for (int i = 0; i < 4; ++i)
                    dst[(long)(r0 + m * 16 + i) * CC + c0 + n * 16] =
                        f2bf(acc[m][n][i] * sc);
    }
}

__global__ __launch_bounds__(256) void out_gemm(const u16* __restrict__ at,
                                                const u16* __restrict__ wob,
                                                const float* __restrict__ bias,
                                                float* __restrict__ out) {
    __shared__ u16 smem[4][128 * 32];
    int bid = blockIdx.x;
    int blkM = bid & 31, blkN = bid >> 5;
    f32x4 acc[4][4];
    gemm_core(at, wob, blkM, blkN, smem[0], smem[1], smem[2], smem[3], acc);

    int lane = threadIdx.x & 63;
    int w = threadIdx.x >> 6, wr = w >> 1, wc = w & 1;
    int l15 = lane & 15, hi = lane >> 4;
    int r0 = blkM * 128 + wr * 64 + hi * 4;
    int c0 = blkN * 128 + wc * 64 + l15;
#pragma unroll
    for (int n = 0; n < 4; ++n) {
        int c = c0 + n * 16;
        float bv = bias[c];
#pragma unroll
        for (int m = 0; m < 4; ++m)
#pragma unroll
            for (int i = 0; i < 4; ++i)
                out[(long)(r0 + m * 16 + i) * CC + c] = acc[m][n][i] + bv;
    }
}

// ---------------------------------------------------------------- flash attention v13
// = v8 split-KV structure + T3/T4 pipeline: double-buffered K/V with COUNTED
// s_waitcnt vmcnt(8) + raw s_barrier (tile j+1's loads stay in flight across the
// barrier while tile j computes). T5 setprio around MFMA clusters.
// Block = 2 waves on same 32 q-rows; wave w takes kv-half w of each 64-kv tile.
#define PSTR2 36   // P row stride (u16): 72B, 8B-aligned

__global__ __launch_bounds__(128) void attn_fwd(const u16* __restrict__ Q,
                                                const u16* __restrict__ Kb,
                                                const u16* __restrict__ Vt,
                                                u16* __restrict__ O) {
    __shared__ u16 sK[2][64 * 64];      // 16 KB dbuf (also merge scratch at end)
    __shared__ u16 sV[2][64 * 64];      // 16 KB dbuf
    __shared__ u16 sP[2][32 * PSTR2];   // 4.6 KB

    int lane = threadIdx.x & 63;
    int w = threadIdx.x >> 6;           // 0..1 = kv-half of each staged tile
    int bh = blockIdx.x & 31;           // same bh -> same XCD (idx&7 = bh&7)
    int qt = 63 - (blockIdx.x >> 5);    // q-tile of 32 rows, heaviest first (LPT)
    int h = bh & 15, b = bh >> 4;
    int l31 = lane & 31, h5 = lane >> 5;

    int qg = qt * 32 + l31;             // this lane's q row
    int nt32 = qt + 1;                  // 32-kv subtiles needed
    int J = (qt >> 1) + 1;              // staged 64-kv iterations (uniform)

    const u16* Kgb = Kb + (long)(b * TT) * CC + h * SS;
    const u16* Vgb = Vt + (long)(h * SS) * MM + b * TT;
    u16* Pw = sP[w];

    // per-thread staging pointers, advanced 64 kv rows per stage
    int t0 = threadIdx.x;
    const u16* kp[4];
    const u16* vp[4];
    int ldo[4];
#pragma unroll
    for (int q = 0; q < 4; ++q) {
        int c = q * 128 + t0;           // 16B chunk 0..511
        int row = c >> 3, col = c & 7;
        int scol = col ^ (row & 7);     // pre-swizzled source chunk
        kp[q] = Kgb + (long)row * CC + scol * 8;
        vp[q] = Vgb + (long)row * MM + scol * 8;
        ldo[q] = c * 8;
    }

#define STAGE_KV(dK_, dV_)                                                        \
    do {                                                                          \
        _Pragma("unroll") for (int q = 0; q < 4; ++q) {                           \
            __builtin_amdgcn_global_load_lds(                                     \
                (const __attribute__((address_space(1))) void*)kp[q],             \
                (__attribute__((address_space(3))) void*)((dK_) + ldo[q]), 16, 0, 0); \
            __builtin_amdgcn_global_load_lds(                                     \
                (const __attribute__((address_space(1))) void*)vp[q],             \
                (__attribute__((address_space(3))) void*)((dV_) + ldo[q]), 16, 0, 0); \
            kp[q] += 64 * CC;                                                     \
            vp[q] += 64;                                                          \
        }                                                                         \
    } while (0)

    // Q fragments (B operand): col=l31 (q), k = m*16 + h5*8 + j
    const u16* qrow = Q + (long)(b * TT + qg) * CC + h * SS + h5 * 8;
    bf16x8 qf[4];
#pragma unroll
    for (int m = 0; m < 4; ++m) qf[m] = *(const bf16x8*)(qrow + m * 16);

    f32x16 oa0 = {0.f}, oa1 = {0.f};    // O^T partial: d 0..31 / 32..63, col=q=l31
    float mr = -1e30f, lr = 0.f;

    // prologue: stage tiles 0 and 1 (16 loads in flight)
    STAGE_KV(sK[0], sV[0]);
    if (J > 1) STAGE_KV(sK[1], sV[1]);

#pragma unroll 1
    for (int j = 0; j < J; ++j) {
        // counted wait: tile j's 8 loads done; tile j+1's 8 may stay in flight
        if (j + 1 < J) {
            asm volatile("s_waitcnt vmcnt(8)" ::: "memory");
        } else {
            asm volatile("s_waitcnt vmcnt(0)" ::: "memory");
        }
        __builtin_amdgcn_s_barrier();        // tile j visible to all waves
        __builtin_amdgcn_sched_barrier(0);   // fence: no hoisting above the wait

        const u16* cK = sK[j & 1];
        const u16* cV = sV[j & 1];

        int tt = 2 * j + w;            // this wave's 32-kv subtile index
        if (tt < nt32) {
            // QK^T swapped: S^T = mfma(A=K rows w*32+l31, B=Q)
            f32x16 s0 = {0.f};
            __builtin_amdgcn_s_setprio(1);
#pragma unroll
            for (int m = 0; m < 4; ++m) {
                int ch0 = (((m * 2 + h5) ^ (l31 & 7)) << 3);
                bf16x8 kf = *(const bf16x8*)(cK + (w * 32 + l31) * 64 + ch0);
                s0 = MFMA32(kf, qf[m], s0);
            }
            __builtin_amdgcn_s_setprio(0);

            if (tt == qt) {   // diagonal subtile: causal mask (kv > q)
                int kvb = tt * 32 + 4 * h5;
#pragma unroll
                for (int r = 0; r < 16; ++r) {
                    int kv = kvb + (r & 3) + 8 * (r >> 2);
                    if (kv > qg) s0[r] = -1e30f;
                }
            }

            // subtile max: in-lane tree + one partner exchange
            float t8[8];
#pragma unroll
            for (int r = 0; r < 8; ++r) t8[r] = fmaxf(s0[r], s0[r + 8]);
#pragma unroll
            for (int r = 0; r < 4; ++r) t8[r] = fmaxf(t8[r], t8[r + 4]);
            float tmx = fmaxf(fmaxf(t8[0], t8[1]), fmaxf(t8[2], t8[3]));
            tmx = fmaxf(tmx, __shfl_xor(tmx, 32));

            // defer-max: rescale only when subtile max exceeds running max by > 8
            if (!__all(tmx <= mr + 8.0f)) {
                float mnew = fmaxf(mr, tmx);
                float scl = __builtin_amdgcn_exp2f(mr - mnew);
                lr *= scl;
#pragma unroll
                for (int r = 0; r < 16; ++r) { oa0[r] *= scl; oa1[r] *= scl; }
                mr = mnew;
            }

            // P = exp2(S - mr), bounded by 2^8
            f32x16 p0v;
#pragma unroll
            for (int r = 0; r < 16; ++r) p0v[r] = __builtin_amdgcn_exp2f(s0[r] - mr);
            float sm[8];
#pragma unroll
            for (int r = 0; r < 8; ++r) sm[r] = p0v[r] + p0v[r + 8];
#pragma unroll
            for (int r = 0; r < 4; ++r) sm[r] = sm[r] + sm[r + 4];
            float rs = (sm[0] + sm[1]) + (sm[2] + sm[3]);
            rs += __shfl_xor(rs, 32);
            lr += rs;

            // P -> LDS [q=l31][kv 0..31], packed via cvt_pk (low u16 = src0)
#pragma unroll
            for (int r4 = 0; r4 < 4; ++r4) {
                unsigned a0, a1;
                CVTPK(a0, p0v[r4 * 4 + 0], p0v[r4 * 4 + 1]);
                CVTPK(a1, p0v[r4 * 4 + 2], p0v[r4 * 4 + 3]);
                uint2 ua;
                ua.x = a0; ua.y = a1;
                *(uint2*)(Pw + l31 * PSTR2 + 8 * r4 + 4 * h5) = ua;
            }

            // PV: O^T[d][q] += V[d][kv] * P^T[kv][q]; kv range = w*32..w*32+31
            bf16x8 pf0 = *(const bf16x8*)(Pw + l31 * PSTR2 + 8 * h5);
            bf16x8 pf1 = *(const bf16x8*)(Pw + l31 * PSTR2 + 16 + 8 * h5);
            int ch0 = (((4 * w + h5) ^ (l31 & 7)) << 3);
            int ch1 = (((4 * w + 2 + h5) ^ (l31 & 7)) << 3);
            bf16x8 v00 = *(const bf16x8*)(cV + l31 * 64 + ch0);
            bf16x8 v01 = *(const bf16x8*)(cV + l31 * 64 + ch1);
            bf16x8 v10 = *(const bf16x8*)(cV + (32 + l31) * 64 + ch0);
            bf16x8 v11 = *(const bf16x8*)(cV + (32 + l31) * 64 + ch1);
            __builtin_amdgcn_s_setprio(1);
            oa0 = MFMA32(v00, pf0, oa0);
            oa0 = MFMA32(v01, pf1, oa0);
            oa1 = MFMA32(v10, pf0, oa1);
            oa1 = MFMA32(v11, pf1, oa1);
            __builtin_amdgcn_s_setprio(0);
        }

        __builtin_amdgcn_s_barrier();   // all waves done reading buf[j&1]
        if (j + 2 < J) STAGE_KV(sK[j & 1], sV[j & 1]);   // refill freed buffer
    }

    // ---- merge the two kv-half partials (per-lane elementwise; same layout) ----
    __syncthreads();                   // loop done; reuse sK as merge scratch
    float* xch = (float*)sK;           // 64 lanes x 36 f32 = 9216 B (< 16 KB)
    if (w == 1) {
        float* xl = xch + lane * 36;
#pragma unroll
        for (int r = 0; r < 16; ++r) { xl[r] = oa0[r]; xl[16 + r] = oa1[r]; }
        xl[32] = mr; xl[33] = lr;
    }
    __syncthreads();
    if (w == 0) {
        float* xl = xch + lane * 36;
        float m1 = xl[32], l1 = xl[33];
        float m = fmaxf(mr, m1);
        float e0 = __builtin_amdgcn_exp2f(mr - m);
        float e1 = __builtin_amdgcn_exp2f(m1 - m);
        float inv = 1.0f / (lr * e0 + l1 * e1);
        float f0 = e0 * inv, f1 = e1 * inv;

        u16* ob = O + (long)(b * TT + qg) * CC + h * SS;
#pragma unroll
        for (int rq = 0; rq < 4; ++rq) {
            float v00 = oa0[rq * 4 + 0] * f0 + xl[rq * 4 + 0] * f1;
            float v01 = oa0[rq * 4 + 1] * f0 + xl[rq * 4 + 1] * f1;
            float v02 = oa0[rq * 4 + 2] * f0 + xl[rq * 4 + 2] * f1;
            float v03 = oa0[rq * 4 + 3] * f0 + xl[rq * 4 + 3] * f1;
            float v10 = oa1[rq * 4 + 0] * f0 + xl[16 + rq * 4 + 0] * f1;
            float v11 = oa1[rq * 4 + 1] * f0 + xl[16 + rq * 4 + 1] * f1;
            float v12 = oa1[rq * 4 + 2] * f0 + xl[16 + rq * 4 + 2] * f1;
            float v13 = oa1[rq * 4 + 3] * f0 + xl[16 + rq * 4 + 3] * f1;
            unsigned a0, a1, c0, c1;
            CVTPK(a0, v00, v01);
            CVTPK(a1, v02, v03);
            CVTPK(c0, v10, v11);
            CVTPK(c1, v12, v13);
            uint2 ua, uc;
            ua.x = a0; ua.y = a1; uc.x = c0; uc.y = c1;
            *(uint2*)(ob + rq * 8 + h5 * 4) = ua;
            *(uint2*)(ob + 32 + rq * 8 + h5 * 4) = uc;
        }
    }
#undef STAGE_KV
}

// ---------------------------------------------------------------- launch
extern "C" void kernel_launch(void* const* d_in, const int* in_sizes, int n_in,
                              void* d_out, int out_size, void* d_ws, size_t ws_size,
                              hipStream_t stream) {
    const float* x  = (const float*)d_in[0];
    const float* Wq = (const float*)d_in[1];
    const float* Wk = (const float*)d_in[2];
    const float* Wv = (const float*)d_in[3];
    const float* Wo = (const float*)d_in[4];
    const float* bo = (const float*)d_in[5];

    char* ws = (char*)d_ws;
    const size_t MB = 1024 * 1024;
    u16* x_bf  = (u16*)(ws);
    u16* wq_bf = (u16*)(ws + 8 * MB);
    u16* wk_bf = (u16*)(ws + 10 * MB);
    u16* wv_bf = (u16*)(ws + 12 * MB);
    u16* wo_bf = (u16*)(ws + 14 * MB);
    u16* q_bf  = (u16*)(ws + 16 * MB);
    u16* k_bf  = (u16*)(ws + 24 * MB);
    u16* vt_bf = (u16*)(ws + 32 * MB);   // [1024][4096] transposed V
    u16* at_bf = (u16*)(ws + 40 * MB);

    cast_all<<<dim3(8192), dim3(256), 0, stream>>>(
        (const float4*)x, (const float4*)Wq, (const float4*)Wk,
        (const float4*)Wv, (const float4*)Wo,
        (ushort4*)x_bf, (ushort4*)wq_bf, (ushort4*)wk_bf,
        (ushort4*)wv_bf, (ushort4*)wo_bf);

    qkv_gemm<<<dim3(768), dim3(256), 0, stream>>>(x_bf, wq_bf, wk_bf, wv_bf,
                                                  q_bf, k_bf, vt_bf);

    attn_fwd<<<dim3(2048), dim3(128), 0, stream>>>(q_bf, k_bf, vt_bf, at_bf);

    out_gemm<<<dim3(256), dim3(256), 0, stream>>>(at_bf, wo_bf, bo, (float*)d_out);
}

// Round 14
// 112.912 us; speedup vs baseline: 1.2224x; 1.0732x over previous
//
#include <hip/hip_runtime.h>

// Problem constants: B=2, T=2048, C=1024, H=16, S=64
#define BB 2
#define TT 2048
#define CC 1024
#define HH 16
#define SS 64
#define MM (BB * TT)   // 4096

typedef unsigned short u16;
typedef __bf16 bf16x8 __attribute__((ext_vector_type(8)));
typedef float f32x4 __attribute__((ext_vector_type(4)));
typedef float f32x16 __attribute__((ext_vector_type(16)));

#define MFMA16(a, b, c) __builtin_amdgcn_mfma_f32_16x16x32_bf16((a), (b), (c), 0, 0, 0)
#define MFMA32(a, b, c) __builtin_amdgcn_mfma_f32_32x32x16_bf16((a), (b), (c), 0, 0, 0)
// v_cvt_pk_bf16_f32: D[15:0]=bf16(S0), D[31:16]=bf16(S1)
#define CVTPK(d, a, b) asm("v_cvt_pk_bf16_f32 %0, %1, %2" : "=v"(d) : "v"(a), "v"(b))

__device__ inline u16 f2bf(float f) {
    union { float f; unsigned u; } v;
    v.f = f;
    unsigned r = v.u + 0x7FFFu + ((v.u >> 16) & 1u);
    return (u16)(r >> 16);
}

// ---------------------------------------------------------------- fused casts
__global__ __launch_bounds__(256) void cast_all(
    const float4* __restrict__ x,  const float4* __restrict__ wq,
    const float4* __restrict__ wk, const float4* __restrict__ wv,
    const float4* __restrict__ wo,
    ushort4* __restrict__ xo, ushort4* __restrict__ qo,
    ushort4* __restrict__ ko, ushort4* __restrict__ vo,
    ushort4* __restrict__ oo) {
    int bid = blockIdx.x;
    const float4* src; ushort4* dst; int i;
    if (bid < 4096) {
        src = x; dst = xo; i = bid * 256 + threadIdx.x;
    } else {
        int s = (bid - 4096) >> 10;
        int r = (bid - 4096) & 1023;
        src = (s == 0) ? wq : (s == 1) ? wk : (s == 2) ? wv : wo;
        dst = (s == 0) ? qo : (s == 1) ? ko : (s == 2) ? vo : oo;
        i = r * 256 + threadIdx.x;
    }
    float4 v = src[i];
    ushort4 o;
    o.x = f2bf(v.x); o.y = f2bf(v.y); o.z = f2bf(v.z); o.w = f2bf(v.w);
    dst[i] = o;
}

// ---------------------------------------------------------------- 128x128 GEMM core
__device__ __forceinline__ void stage_tile(const u16* __restrict__ g, int row0, int k0,
                                           u16* lds) {
    int t = threadIdx.x;
#pragma unroll
    for (int q = 0; q < 2; ++q) {
        int idx = q * 256 + t;
        int row = idx >> 2;
        int chunk = (idx & 3) ^ (row & 3);
        const u16* src = g + (long)(row0 + row) * CC + k0 + chunk * 8;
        __builtin_amdgcn_global_load_lds(
            (const __attribute__((address_space(1))) void*)src,
            (__attribute__((address_space(3))) void*)(lds + idx * 8), 16, 0, 0);
    }
}

__device__ __forceinline__ void gemm_core(const u16* __restrict__ A,
                                          const u16* __restrict__ Bt,
                                          int blkM, int blkN,
                                          u16* sA0, u16* sB0, u16* sA1, u16* sB1,
                                          f32x4 (&acc)[4][4]) {
    int lane = threadIdx.x & 63;
    int w = threadIdx.x >> 6;
    int wr = w >> 1, wc = w & 1;
    int l15 = lane & 15;
    int hi = lane >> 4;

#pragma unroll
    for (int m = 0; m < 4; ++m)
#pragma unroll
        for (int n = 0; n < 4; ++n) acc[m][n] = (f32x4){0.f, 0.f, 0.f, 0.f};

    stage_tile(A, blkM * 128, 0, sA0);
    stage_tile(Bt, blkN * 128, 0, sB0);

    for (int kt = 0; kt < CC / 32; ++kt) {
        __syncthreads();
        u16* cA = (kt & 1) ? sA1 : sA0;
        u16* cB = (kt & 1) ? sB1 : sB0;
        if (kt + 1 < CC / 32) {
            u16* nA = (kt & 1) ? sA0 : sA1;
            u16* nB = (kt & 1) ? sB0 : sB1;
            stage_tile(A, blkM * 128, (kt + 1) * 32, nA);
            stage_tile(Bt, blkN * 128, (kt + 1) * 32, nB);
        }
        bf16x8 af[4], bfr[4];
#pragma unroll
        for (int m = 0; m < 4; ++m) {
            int row = wr * 64 + m * 16 + l15;
            af[m] = *(const bf16x8*)(cA + row * 32 + ((hi ^ (row & 3)) << 3));
        }
#pragma unroll
        for (int n = 0; n < 4; ++n) {
            int row = wc * 64 + n * 16 + l15;
            bfr[n] = *(const bf16x8*)(cB + row * 32 + ((hi ^ (row & 3)) << 3));
        }
#pragma unroll
        for (int m = 0; m < 4; ++m)
#pragma unroll
            for (int n = 0; n < 4; ++n)
                acc[m][n] = MFMA16(af[m], bfr[n], acc[m][n]);
    }
}

__global__ __launch_bounds__(256) void qkv_gemm(const u16* __restrict__ xb,
                                                const u16* __restrict__ wqb,
                                                const u16* __restrict__ wkb,
                                                const u16* __restrict__ wvb,
                                                u16* __restrict__ qo,
                                                u16* __restrict__ ko,
                                                u16* __restrict__ vt) {
    __shared__ u16 smem[4][128 * 32];
    int seg = blockIdx.x >> 8;
    int bid = blockIdx.x & 255;
    int blkM = bid & 31, blkN = bid >> 5;
    const u16* Bt = (seg == 0) ? wqb : (seg == 1) ? wkb : wvb;
    f32x4 acc[4][4];
    gemm_core(xb, Bt, blkM, blkN, smem[0], smem[1], smem[2], smem[3], acc);

    int lane = threadIdx.x & 63;
    int w = threadIdx.x >> 6, wr = w >> 1, wc = w & 1;
    int l15 = lane & 15, hi = lane >> 4;
    int r0 = blkM * 128 + wr * 64 + hi * 4;
    int c0 = blkN * 128 + wc * 64 + l15;

    if (seg == 2) {
#pragma unroll
        for (int m = 0; m < 4; ++m)
#pragma unroll
            for (int n = 0; n < 4; ++n) {
                ushort4 p;
                p.x = f2bf(acc[m][n][0]); p.y = f2bf(acc[m][n][1]);
                p.z = f2bf(acc[m][n][2]); p.w = f2bf(acc[m][n][3]);
                *(ushort4*)(vt + (long)(c0 + n * 16) * MM + r0 + m * 16) = p;
            }
    } else {
        u16* dst = (seg == 0) ? qo : ko;
        // Q pre-scaled by 1/sqrt(64) * log2(e): exp2-domain softmax
        float sc = (seg == 0) ? 0.18033688011112042f : 1.0f;
#pragma unroll
        for (int m = 0; m < 4; ++m)
#pragma unroll
            for (int n = 0; n < 4; ++n)
#pragma unroll
                for (int i = 0; i < 4; ++i)
                    dst[(long)(r0 + m * 16 + i) * CC + c0 + n * 16] =
                        f2bf(acc[m][n][i] * sc);
    }
}

__global__ __launch_bounds__(256) void out_gemm(const u16* __restrict__ at,
                                                const u16* __restrict__ wob,
                                                const float* __restrict__ bias,
                                                float* __restrict__ out) {
    __shared__ u16 smem[4][128 * 32];
    int bid = blockIdx.x;
    int blkM = bid & 31, blkN = bid >> 5;
    f32x4 acc[4][4];
    gemm_core(at, wob, blkM, blkN, smem[0], smem[1], smem[2], smem[3], acc);

    int lane = threadIdx.x & 63;
    int w = threadIdx.x >> 6, wr = w >> 1, wc = w & 1;
    int l15 = lane & 15, hi = lane >> 4;
    int r0 = blkM * 128 + wr * 64 + hi * 4;
    int c0 = blkN * 128 + wc * 64 + l15;
#pragma unroll
    for (int n = 0; n < 4; ++n) {
        int c = c0 + n * 16;
        float bv = bias[c];
#pragma unroll
        for (int m = 0; m < 4; ++m)
#pragma unroll
            for (int i = 0; i < 4; ++i)
                out[(long)(r0 + m * 16 + i) * CC + c] = acc[m][n][i] + bv;
    }
}

// ---------------------------------------------------------------- flash attention v14
// = v13 (split-KV + counted-vmcnt dbuf pipeline) with the P-LDS roundtrip replaced
// by IN-REGISTER fragment construction: cvt_pk + v_permlane32_swap_b32, using the
// OPPOSITE operand orientation from R4 (swap(w0,w2) not swap(w2,w0)) — single-
// variable test of the permlane direction. sP removed (LDS 37.4 -> 32.8 KB).
__global__ __launch_bounds__(128) void attn_fwd(const u16* __restrict__ Q,
                                                const u16* __restrict__ Kb,
                                                const u16* __restrict__ Vt,
                                                u16* __restrict__ O) {
    __shared__ u16 sK[2][64 * 64];      // 16 KB dbuf (also merge scratch at end)
    __shared__ u16 sV[2][64 * 64];      // 16 KB dbuf

    int lane = threadIdx.x & 63;
    int w = threadIdx.x >> 6;           // 0..1 = kv-half of each staged tile
    int bh = blockIdx.x & 31;           // same bh -> same XCD (idx&7 = bh&7)
    int qt = 63 - (blockIdx.x >> 5);    // q-tile of 32 rows, heaviest first (LPT)
    int h = bh & 15, b = bh >> 4;
    int l31 = lane & 31, h5 = lane >> 5;

    int qg = qt * 32 + l31;             // this lane's q row
    int nt32 = qt + 1;                  // 32-kv subtiles needed
    int J = (qt >> 1) + 1;              // staged 64-kv iterations (uniform)

    const u16* Kgb = Kb + (long)(b * TT) * CC + h * SS;
    const u16* Vgb = Vt + (long)(h * SS) * MM + b * TT;

    // per-thread staging pointers, advanced 64 kv rows per stage
    int t0 = threadIdx.x;
    const u16* kp[4];
    const u16* vp[4];
    int ldo[4];
#pragma unroll
    for (int q = 0; q < 4; ++q) {
        int c = q * 128 + t0;           // 16B chunk 0..511
        int row = c >> 3, col = c & 7;
        int scol = col ^ (row & 7);     // pre-swizzled source chunk
        kp[q] = Kgb + (long)row * CC + scol * 8;
        vp[q] = Vgb + (long)row * MM + scol * 8;
        ldo[q] = c * 8;
    }

#define STAGE_KV(dK_, dV_)                                                        \
    do {                                                                          \
        _Pragma("unroll") for (int q = 0; q < 4; ++q) {                           \
            __builtin_amdgcn_global_load_lds(                                     \
                (const __attribute__((address_space(1))) void*)kp[q],             \
                (__attribute__((address_space(3))) void*)((dK_) + ldo[q]), 16, 0, 0); \
            __builtin_amdgcn_global_load_lds(                                     \
                (const __attribute__((address_space(1))) void*)vp[q],             \
                (__attribute__((address_space(3))) void*)((dV_) + ldo[q]), 16, 0, 0); \
            kp[q] += 64 * CC;                                                     \
            vp[q] += 64;                                                          \
        }                                                                         \
    } while (0)

    // Q fragments (B operand): col=l31 (q), k = m*16 + h5*8 + j
    const u16* qrow = Q + (long)(b * TT + qg) * CC + h * SS + h5 * 8;
    bf16x8 qf[4];
#pragma unroll
    for (int m = 0; m < 4; ++m) qf[m] = *(const bf16x8*)(qrow + m * 16);

    f32x16 oa0 = {0.f}, oa1 = {0.f};    // O^T partial: d 0..31 / 32..63, col=q=l31
    float mr = -1e30f, lr = 0.f;

    // prologue: stage tiles 0 and 1 (16 loads in flight)
    STAGE_KV(sK[0], sV[0]);
    if (J > 1) STAGE_KV(sK[1], sV[1]);

#pragma unroll 1
    for (int j = 0; j < J; ++j) {
        // counted wait: tile j's 8 loads done; tile j+1's 8 may stay in flight
        if (j + 1 < J) {
            asm volatile("s_waitcnt vmcnt(8)" ::: "memory");
        } else {
            asm volatile("s_waitcnt vmcnt(0)" ::: "memory");
        }
        __builtin_amdgcn_s_barrier();        // tile j visible to all waves
        __builtin_amdgcn_sched_barrier(0);   // fence: no hoisting above the wait

        const u16* cK = sK[j & 1];
        const u16* cV = sV[j & 1];

        int tt = 2 * j + w;            // this wave's 32-kv subtile index
        if (tt < nt32) {
            // QK^T swapped: S^T = mfma(A=K rows w*32+l31, B=Q)
            f32x16 s0 = {0.f};
            __builtin_amdgcn_s_setprio(1);
#pragma unroll
            for (int m = 0; m < 4; ++m) {
                int ch0 = (((m * 2 + h5) ^ (l31 & 7)) << 3);
                bf16x8 kf = *(const bf16x8*)(cK + (w * 32 + l31) * 64 + ch0);
                s0 = MFMA32(kf, qf[m], s0);
            }
            __builtin_amdgcn_s_setprio(0);

            // hoist V fragment loads (independent of scores) for ILP
            int chv0 = (((4 * w + h5) ^ (l31 & 7)) << 3);
            int chv1 = (((4 * w + 2 + h5) ^ (l31 & 7)) << 3);
            bf16x8 v00 = *(const bf16x8*)(cV + l31 * 64 + chv0);
            bf16x8 v01 = *(const bf16x8*)(cV + l31 * 64 + chv1);
            bf16x8 v10 = *(const bf16x8*)(cV + (32 + l31) * 64 + chv0);
            bf16x8 v11 = *(const bf16x8*)(cV + (32 + l31) * 64 + chv1);

            if (tt == qt) {   // diagonal subtile: causal mask (kv > q)
                int kvb = tt * 32 + 4 * h5;
#pragma unroll
                for (int r = 0; r < 16; ++r) {
                    int kv = kvb + (r & 3) + 8 * (r >> 2);
                    if (kv > qg) s0[r] = -1e30f;
                }
            }

            // subtile max: in-lane tree + one partner exchange
            float t8[8];
#pragma unroll
            for (int r = 0; r < 8; ++r) t8[r] = fmaxf(s0[r], s0[r + 8]);
#pragma unroll
            for (int r = 0; r < 4; ++r) t8[r] = fmaxf(t8[r], t8[r + 4]);
            float tmx = fmaxf(fmaxf(t8[0], t8[1]), fmaxf(t8[2], t8[3]));
            tmx = fmaxf(tmx, __shfl_xor(tmx, 32));

            // defer-max: rescale only when subtile max exceeds running max by > 8
            if (!__all(tmx <= mr + 8.0f)) {
                float mnew = fmaxf(mr, tmx);
                float scl = __builtin_amdgcn_exp2f(mr - mnew);
                lr *= scl;
#pragma unroll
                for (int r = 0; r < 16; ++r) { oa0[r] *= scl; oa1[r] *= scl; }
                mr = mnew;
            }

            // P = exp2(S - mr), bounded by 2^8
            f32x16 p0v;
#pragma unroll
            for (int r = 0; r < 16; ++r) p0v[r] = __builtin_amdgcn_exp2f(s0[r] - mr);
            float sm[8];
#pragma unroll
            for (int r = 0; r < 8; ++r) sm[r] = p0v[r] + p0v[r + 8];
#pragma unroll
            for (int r = 0; r < 4; ++r) sm[r] = sm[r] + sm[r + 4];
            float rs = (sm[0] + sm[1]) + (sm[2] + sm[3]);
            rs += __shfl_xor(rs, 32);
            lr += rs;

            // In-register P -> B-fragment: cvt_pk + permlane32_swap.
            // Orientation: swap(w0, w2) — opposite of R4's failed swap(w2, w0).
            bf16x8 pf[2];
#pragma unroll
            for (int hk = 0; hk < 2; ++hk) {
                unsigned w0, w1, w2, w3;
                CVTPK(w0, p0v[8 * hk + 0], p0v[8 * hk + 1]);
                CVTPK(w1, p0v[8 * hk + 2], p0v[8 * hk + 3]);
                CVTPK(w2, p0v[8 * hk + 4], p0v[8 * hk + 5]);
                CVTPK(w3, p0v[8 * hk + 6], p0v[8 * hk + 7]);
                asm("v_permlane32_swap_b32 %0, %1" : "+v"(w0), "+v"(w2));
                asm("v_permlane32_swap_b32 %0, %1" : "+v"(w1), "+v"(w3));
                union { unsigned u[4]; bf16x8 v; } fb;
                fb.u[0] = w0; fb.u[1] = w1; fb.u[2] = w2; fb.u[3] = w3;
                pf[hk] = fb.v;
            }

            // PV: O^T[d][q] += V[d][kv] * P^T[kv][q]; kv range = w*32..w*32+31
            __builtin_amdgcn_s_setprio(1);
            oa0 = MFMA32(v00, pf[0], oa0);
            oa0 = MFMA32(v01, pf[1], oa0);
            oa1 = MFMA32(v10, pf[0], oa1);
            oa1 = MFMA32(v11, pf[1], oa1);
            __builtin_amdgcn_s_setprio(0);
        }

        __builtin_amdgcn_s_barrier();   // all waves done reading buf[j&1]
        if (j + 2 < J) STAGE_KV(sK[j & 1], sV[j & 1]);   // refill freed buffer
    }

    // ---- merge the two kv-half partials (per-lane elementwise; same layout) ----
    __syncthreads();                   // loop done; reuse sK as merge scratch
    float* xch = (float*)sK;           // 64 lanes x 36 f32 = 9216 B (< 16 KB)
    if (w == 1) {
        float* xl = xch + lane * 36;
#pragma unroll
        for (int r = 0; r < 16; ++r) { xl[r] = oa0[r]; xl[16 + r] = oa1[r]; }
        xl[32] = mr; xl[33] = lr;
    }
    __syncthreads();
    if (w == 0) {
        float* xl = xch + lane * 36;
        float m1 = xl[32], l1 = xl[33];
        float m = fmaxf(mr, m1);
        float e0 = __builtin_amdgcn_exp2f(mr - m);
        float e1 = __builtin_amdgcn_exp2f(m1 - m);
        float inv = 1.0f / (lr * e0 + l1 * e1);
        float f0 = e0 * inv, f1 = e1 * inv;

        u16* ob = O + (long)(b * TT + qg) * CC + h * SS;
#pragma unroll
        for (int rq = 0; rq < 4; ++rq) {
            float v00 = oa0[rq * 4 + 0] * f0 + xl[rq * 4 + 0] * f1;
            float v01 = oa0[rq * 4 + 1] * f0 + xl[rq * 4 + 1] * f1;
            float v02 = oa0[rq * 4 + 2] * f0 + xl[rq * 4 + 2] * f1;
            float v03 = oa0[rq * 4 + 3] * f0 + xl[rq * 4 + 3] * f1;
            float v10 = oa1[rq * 4 + 0] * f0 + xl[16 + rq * 4 + 0] * f1;
            float v11 = oa1[rq * 4 + 1] * f0 + xl[16 + rq * 4 + 1] * f1;
            float v12 = oa1[rq * 4 + 2] * f0 + xl[16 + rq * 4 + 2] * f1;
            float v13 = oa1[rq * 4 + 3] * f0 + xl[16 + rq * 4 + 3] * f1;
            unsigned a0, a1, c0, c1;
            CVTPK(a0, v00, v01);
            CVTPK(a1, v02, v03);
            CVTPK(c0, v10, v11);
            CVTPK(c1, v12, v13);
            uint2 ua, uc;
            ua.x = a0; ua.y = a1; uc.x = c0; uc.y = c1;
            *(uint2*)(ob + rq * 8 + h5 * 4) = ua;
            *(uint2*)(ob + 32 + rq * 8 + h5 * 4) = uc;
        }
    }
#undef STAGE_KV
}

// ---------------------------------------------------------------- launch
extern "C" void kernel_launch(void* const* d_in, const int* in_sizes, int n_in,
                              void* d_out, int out_size, void* d_ws, size_t ws_size,
                              hipStream_t stream) {
    const float* x  = (const float*)d_in[0];
    const float* Wq = (const float*)d_in[1];
    const float* Wk = (const float*)d_in[2];
    const float* Wv = (const float*)d_in[3];
    const float* Wo = (const float*)d_in[4];
    const float* bo = (const float*)d_in[5];

    char* ws = (char*)d_ws;
    const size_t MB = 1024 * 1024;
    u16* x_bf  = (u16*)(ws);
    u16* wq_bf = (u16*)(ws + 8 * MB);
    u16* wk_bf = (u16*)(ws + 10 * MB);
    u16* wv_bf = (u16*)(ws + 12 * MB);
    u16* wo_bf = (u16*)(ws + 14 * MB);
    u16* q_bf  = (u16*)(ws + 16 * MB);
    u16* k_bf  = (u16*)(ws + 24 * MB);
    u16* vt_bf = (u16*)(ws + 32 * MB);   // [1024][4096] transposed V
    u16* at_bf = (u16*)(ws + 40 * MB);

    cast_all<<<dim3(8192), dim3(256), 0, stream>>>(
        (const float4*)x, (const float4*)Wq, (const float4*)Wk,
        (const float4*)Wv, (const float4*)Wo,
        (ushort4*)x_bf, (ushort4*)wq_bf, (ushort4*)wk_bf,
        (ushort4*)wv_bf, (ushort4*)wo_bf);

    qkv_gemm<<<dim3(768), dim3(256), 0, stream>>>(x_bf, wq_bf, wk_bf, wv_bf,
                                                  q_bf, k_bf, vt_bf);

    attn_fwd<<<dim3(2048), dim3(128), 0, stream>>>(q_bf, k_bf, vt_bf, at_bf);

    out_gemm<<<dim3(256), dim3(256), 0, stream>>>(at_bf, wo_bf, bo, (float*)d_out);
}